// Round 6
// baseline (172.394 us; speedup 1.0000x reference)
//
#include <hip/hip_runtime.h>
#include <math.h>

#define Hdim 768
#define I2   1536
#define Idim 768
#define Edim 128
#define Bdim 32
#define TOPK 4
#define CHUNK 4
#define PARTS1 96   // mlp1: 768/96 = 8 h-rows (16 w1 rows, 48KB)/block
#define PARTS2 48   // mlp2: 768/48 = 16 out-rows (48KB)/block

// nontemporal load of a float4 (weights are streamed exactly once per call:
// rows are exclusive per (expert,part) block; keeping them out of L2/MALL
// preserves the reused t_ws/h_ws/combo lines -> r4: 121 -> 105 us).
typedef float nvec4 __attribute__((ext_vector_type(4)));
__device__ __forceinline__ float4 NT4(const float4* p) {
    nvec4 v = __builtin_nontemporal_load((const nvec4*)p);
    return make_float4(v.x, v.y, v.z, v.w);
}

// ---------------- Kernel 1: fused RMSNorm + gate GEMV + top4 + softmax + packed routing ----------------
// grid = 32 blocks (one per token), 256 threads
__global__ __launch_bounds__(256) void k_prep(
    const float* __restrict__ x, const float* __restrict__ ns,
    const float* __restrict__ gw, float* __restrict__ t_ws,
    int* __restrict__ combo, float* __restrict__ out) {
    __shared__ __align__(16) float t_lds[Hdim];
    __shared__ float red_s[4];
    __shared__ __align__(16) float4 acc_s[4][32];
    __shared__ __align__(16) float gval[Edim];
    __shared__ int   sel_s[TOPK];
    __shared__ float w_s[TOPK];
    const int b    = blockIdx.x;
    const int tid  = threadIdx.x;
    const int w    = tid >> 6;
    const int lane = tid & 63;
    const float* xr = x + b * Hdim;

    // ---- RMSNorm ----
    float ss = 0.f;
    for (int i = tid; i < Hdim; i += 256) { float v = xr[i]; ss += v * v; }
#pragma unroll
    for (int off = 1; off < 64; off <<= 1) ss += __shfl_xor(ss, off, 64);
    if (lane == 0) red_s[w] = ss;
    __syncthreads();
    const float rs = rsqrtf((red_s[0] + red_s[1] + red_s[2] + red_s[3]) / (float)Hdim + 1e-5f);
    for (int i = tid; i < Hdim; i += 256) {
        float xv = xr[i];
        float tv = xv * rs * ns[i];
        t_lds[i] = tv;
        t_ws[b * Hdim + i] = tv;
        out[b * Hdim + i] = xv;          // init out = x (mlp2 atomically adds)
    }
    __syncthreads();

    // ---- gate GEMV: thread = (slice s = tid>>5 of 8, expert group g = tid&31 of 4) ----
    const int g = tid & 31;
    const int s = tid >> 5;
    const float* gwp = gw + (size_t)(s * 96) * Edim + 4 * g;
    float4 a = {0.f, 0.f, 0.f, 0.f};
#pragma unroll 8
    for (int h = 0; h < 96; ++h) {
        float tv = t_lds[s * 96 + h];
        float4 wv = *(const float4*)(gwp + (size_t)h * Edim);
        a.x += tv * wv.x; a.y += tv * wv.y;
        a.z += tv * wv.z; a.w += tv * wv.w;
    }
    a.x += __shfl_xor(a.x, 32, 64); a.y += __shfl_xor(a.y, 32, 64);
    a.z += __shfl_xor(a.z, 32, 64); a.w += __shfl_xor(a.w, 32, 64);
    if (lane < 32) acc_s[w][lane] = a;
    __syncthreads();

    if (w == 0) {
        if (lane < 32) {
            float4 s0 = acc_s[0][lane], s1 = acc_s[1][lane], s2 = acc_s[2][lane], s3 = acc_s[3][lane];
            float4 t4 = {s0.x + s1.x + s2.x + s3.x, s0.y + s1.y + s2.y + s3.y,
                         s0.z + s1.z + s2.z + s3.z, s0.w + s1.w + s2.w + s3.w};
            *(float4*)&gval[4 * lane] = t4;
        }
        // wave-0-only top-4: lane holds experts lane and lane+64
        float g0 = gval[lane], g1 = gval[lane + 64];
        bool p0 = false, p1 = false;
        float topv[TOPK]; int topi[TOPK];
#pragma unroll
        for (int k = 0; k < TOPK; ++k) {
            float c0 = p0 ? -3.0e38f : g0;
            float c1 = p1 ? -3.0e38f : g1;
            float v = fmaxf(c0, c1);
#pragma unroll
            for (int off = 1; off < 64; off <<= 1) v = fmaxf(v, __shfl_xor(v, off, 64));
            int cand = (c0 == v) ? lane : ((c1 == v) ? lane + 64 : 0x7fffffff);
#pragma unroll
            for (int off = 1; off < 64; off <<= 1) cand = min(cand, __shfl_xor(cand, off, 64));
            if (cand == lane) p0 = true;
            if (cand == lane + 64) p1 = true;
            topv[k] = v; topi[k] = cand;
        }
        if (lane == 0) {
            float m = topv[0], ex[TOPK], sum = 0.f;
#pragma unroll
            for (int k = 0; k < TOPK; ++k) { ex[k] = __expf(topv[k] - m); sum += ex[k]; }
            float inv = 1.0f / sum;
#pragma unroll
            for (int k = 0; k < TOPK; ++k) { sel_s[k] = topi[k]; w_s[k] = ex[k] * inv; }
        }
    }
    __syncthreads();
    // packed dense routing table: weight (low 2 mantissa bits cleared) | slot in low 2 bits
    if (tid < Edim) {
        int rv = 0;
#pragma unroll
        for (int k = 0; k < TOPK; ++k)
            if (sel_s[k] == tid)
                rv = (int)((__float_as_uint(w_s[k]) & ~3u) | (unsigned)k);
        combo[tid * Bdim + b] = rv;
    }
}

// ---------------- Kernel 2: mlp1 GEMV + bias + SwiGLU ----------------
// launch_bounds(256,8): 8 waves/EU -> 8 blocks/CU (VGPR<=64; measured 44 at (256,4)).
// Doubles resident weight streams per CU to hide each block's serial preamble
// (combo miss -> ballot -> t stage -> barrier) and retire/dispatch bubbles.
__global__ __launch_bounds__(256, 8) void k_mlp1(
    const float* __restrict__ w1, const float* __restrict__ b1,
    const float* __restrict__ t_ws, const int* __restrict__ combo,
    float* __restrict__ h_ws) {
    const int e    = blockIdx.x / PARTS1;
    const int part = blockIdx.x % PARTS1;
    __shared__ float4 t_lds[CHUNK][Hdim / 4];   // 12 KiB
    __shared__ float  b1_lds[16];
    __shared__ int    pair_s[Bdim];
    __shared__ int    cnt_s;
    const int tid  = threadIdx.x;
    const int wave = tid >> 6, lane = tid & 63;

    // build token list for this expert from the packed table
    if (tid < 64) {
        int rv = (lane < Bdim) ? combo[e * Bdim + lane] : 0;
        float wv = __uint_as_float((unsigned)rv & ~3u);
        unsigned long long m = __ballot(wv > 0.f);
        if (wv > 0.f) {
            int idx = __popcll(m & ((1ull << lane) - 1ull));
            pair_s[idx] = lane * TOPK + (rv & 3);
        }
        if (lane == 0) cnt_s = (int)__popcll(m);
    }
    __syncthreads();
    const int count = cnt_s;
    if (count == 0) return;

    const int jbase = part * (Idim / PARTS1);    // 8 h-rows per block
    const float* w1e = w1 + (size_t)e * I2 * Hdim;
    if (tid < 16) b1_lds[tid] = b1[e * I2 + 2 * jbase + tid];

    for (int i0 = 0; i0 < count; i0 += CHUNK) {
        const int nt = min(CHUNK, count - i0);
        __syncthreads();   // protect LDS reuse across chunks (and order b1/pair writes)
        for (int i = 0; i < nt; ++i) {
            const float4* src = (const float4*)(t_ws + (size_t)(pair_s[i0 + i] >> 2) * Hdim);
            if (tid < Hdim / 4) t_lds[i][tid] = src[tid];
        }
        __syncthreads();
#pragma unroll
        for (int r = 0; r < 2; ++r) {
            const int j = jbase + wave * 2 + r;      // h-row in [0,768)
            const float4* rg = (const float4*)(w1e + (size_t)(2 * j) * Hdim);
            const float4* rl = (const float4*)(w1e + (size_t)(2 * j + 1) * Hdim);
            float4 g0 = NT4(rg + lane), g1 = NT4(rg + lane + 64), g2 = NT4(rg + lane + 128);
            float4 l0 = NT4(rl + lane), l1 = NT4(rl + lane + 64), l2 = NT4(rl + lane + 128);
            float ag[CHUNK], al[CHUNK];
#pragma unroll
            for (int i = 0; i < CHUNK; ++i) {
                ag[i] = 0.f; al[i] = 0.f;
                if (i < nt) {
                    float4 t0 = t_lds[i][lane], t1 = t_lds[i][lane + 64], t2 = t_lds[i][lane + 128];
                    ag[i] = g0.x*t0.x + g0.y*t0.y + g0.z*t0.z + g0.w*t0.w
                          + g1.x*t1.x + g1.y*t1.y + g1.z*t1.z + g1.w*t1.w
                          + g2.x*t2.x + g2.y*t2.y + g2.z*t2.z + g2.w*t2.w;
                    al[i] = l0.x*t0.x + l0.y*t0.y + l0.z*t0.z + l0.w*t0.w
                          + l1.x*t1.x + l1.y*t1.y + l1.z*t1.z + l1.w*t1.w
                          + l2.x*t2.x + l2.y*t2.y + l2.z*t2.z + l2.w*t2.w;
                }
            }
            const float bg = b1_lds[2 * (wave * 2 + r)];
            const float bl = b1_lds[2 * (wave * 2 + r) + 1];
#pragma unroll
            for (int i = 0; i < CHUNK; ++i) {
                if (i < nt) {
                    // parity pair-reduce: even lanes -> sum(ag), odd lanes -> sum(al)
                    const int odd = lane & 1;
                    float send = odd ? ag[i] : al[i];
                    float recv = __shfl_xor(send, 1, 64);
                    float v = (odd ? al[i] : ag[i]) + recv;
#pragma unroll
                    for (int off = 2; off < 64; off <<= 1) v += __shfl_xor(v, off, 64);
                    float vo = __shfl_xor(v, 1, 64);
                    float vg = odd ? vo : v;
                    float vl = odd ? v : vo;
                    float glu = fminf(vg + bg, 7.0f);
                    float lin = fminf(fmaxf(vl + bl, -7.0f), 7.0f);
                    float og = glu / (1.0f + __expf(-1.702f * glu));
                    if (lane == 0)
                        h_ws[(size_t)pair_s[i0 + i] * Idim + j] = og * (lin + 1.0f);
                }
            }
        }
    }
}

// ---------------- Kernel 3: mlp2 GEMV + bias, weighted atomic accumulate into out ----------------
__global__ __launch_bounds__(256, 8) void k_mlp2(
    const float* __restrict__ w2, const float* __restrict__ b2,
    const float* __restrict__ h_ws, const int* __restrict__ combo,
    float* __restrict__ out) {
    const int e    = blockIdx.x / PARTS2;
    const int part = blockIdx.x % PARTS2;
    __shared__ float4 h_lds[CHUNK][Idim / 4];   // 12 KiB
    __shared__ float  b2_lds[16];
    __shared__ int    pair_s[Bdim];
    __shared__ float  wt_s[Bdim];
    __shared__ int    cnt_s;
    const int tid  = threadIdx.x;
    const int wave = tid >> 6, lane = tid & 63;

    if (tid < 64) {
        int rv = (lane < Bdim) ? combo[e * Bdim + lane] : 0;
        float wv = __uint_as_float((unsigned)rv & ~3u);
        unsigned long long m = __ballot(wv > 0.f);
        if (wv > 0.f) {
            int idx = __popcll(m & ((1ull << lane) - 1ull));
            pair_s[idx] = lane * TOPK + (rv & 3);
            wt_s[idx]   = wv;
        }
        if (lane == 0) cnt_s = (int)__popcll(m);
    }
    __syncthreads();
    const int count = cnt_s;
    if (count == 0) return;

    const int cbase = part * (Hdim / PARTS2);    // 16 out-rows per block
    const float* w2e = w2 + (size_t)e * Hdim * Idim;
    if (tid < 16) b2_lds[tid] = b2[e * Hdim + cbase + tid];

    for (int i0 = 0; i0 < count; i0 += CHUNK) {
        const int nt = min(CHUNK, count - i0);
        __syncthreads();
        for (int i = 0; i < nt; ++i) {
            const float4* src = (const float4*)(h_ws + (size_t)pair_s[i0 + i] * Idim);
            if (tid < Idim / 4) h_lds[i][tid] = src[tid];
        }
        __syncthreads();
#pragma unroll
        for (int rp = 0; rp < 2; ++rp) {            // row pairs
            const int c0 = cbase + wave * 4 + 2 * rp;
            const float4* r0 = (const float4*)(w2e + (size_t)c0 * Idim);
            const float4* r1 = (const float4*)(w2e + (size_t)(c0 + 1) * Idim);
            float4 a0 = NT4(r0 + lane), a1 = NT4(r0 + lane + 64), a2 = NT4(r0 + lane + 128);
            float4 d0 = NT4(r1 + lane), d1 = NT4(r1 + lane + 64), d2 = NT4(r1 + lane + 128);
            float ao0[CHUNK], ao1[CHUNK];
#pragma unroll
            for (int i = 0; i < CHUNK; ++i) {
                ao0[i] = 0.f; ao1[i] = 0.f;
                if (i < nt) {
                    float4 h0 = h_lds[i][lane], h1 = h_lds[i][lane + 64], h2 = h_lds[i][lane + 128];
                    ao0[i] = a0.x*h0.x + a0.y*h0.y + a0.z*h0.z + a0.w*h0.w
                           + a1.x*h1.x + a1.y*h1.y + a1.z*h1.z + a1.w*h1.w
                           + a2.x*h2.x + a2.y*h2.y + a2.z*h2.z + a2.w*h2.w;
                    ao1[i] = d0.x*h0.x + d0.y*h0.y + d0.z*h0.z + d0.w*h0.w
                           + d1.x*h1.x + d1.y*h1.y + d1.z*h1.z + d1.w*h1.w
                           + d2.x*h2.x + d2.y*h2.y + d2.z*h2.z + d2.w*h2.w;
                }
            }
#pragma unroll
            for (int i = 0; i < CHUNK; ++i) {
                if (i < nt) {
                    // parity pair-reduce: even lanes -> sum(ao0), odd -> sum(ao1)
                    const int odd = lane & 1;
                    float send = odd ? ao0[i] : ao1[i];
                    float recv = __shfl_xor(send, 1, 64);
                    float v = (odd ? ao1[i] : ao0[i]) + recv;
#pragma unroll
                    for (int off = 2; off < 64; off <<= 1) v += __shfl_xor(v, off, 64);
                    const int c = c0 + odd;
                    if (lane < 2)
                        atomicAdd(&out[(size_t)(pair_s[i0 + i] >> 2) * Hdim + c],
                                  (v + b2_lds[c - cbase]) * wt_s[i0 + i]);
                }
            }
        }
    }
}

extern "C" void kernel_launch(void* const* d_in, const int* in_sizes, int n_in,
                              void* d_out, int out_size, void* d_ws, size_t ws_size,
                              hipStream_t stream) {
    const float* x  = (const float*)d_in[0];
    const float* ns = (const float*)d_in[1];
    const float* gw = (const float*)d_in[2];
    const float* w1 = (const float*)d_in[3];
    const float* b1 = (const float*)d_in[4];
    const float* w2 = (const float*)d_in[5];
    const float* b2 = (const float*)d_in[6];
    float* out = (float*)d_out;
    float* ws  = (float*)d_ws;

    // workspace layout (float offsets)
    float* t_ws  = ws;                     // 32*768  = 24576
    int*   combo = (int*)(ws + 24576);     // 128*32  = 4096 (packed weight|slot)
    float* h_ws  = ws + 28672;             // 128*768 = 98304
    // total: 126976 floats = 507,904 bytes

    k_prep<<<Bdim, 256, 0, stream>>>(x, ns, gw, t_ws, combo, out);
    k_mlp1<<<Edim * PARTS1, 256, 0, stream>>>(w1, b1, t_ws, combo, h_ws);
    k_mlp2<<<Edim * PARTS2, 256, 0, stream>>>(w2, b2, h_ws, combo, out);
}

// Round 7
// 104.899 us; speedup vs baseline: 1.6434x; 1.6434x over previous
//
#include <hip/hip_runtime.h>
#include <math.h>

#define Hdim 768
#define I2   1536
#define Idim 768
#define Edim 128
#define Bdim 32
#define TOPK 4
#define CHUNK 4
#define PARTS1 96   // mlp1: 768/96 = 8 h-rows (16 w1 rows, 48KB)/block
#define PARTS2 48   // mlp2: 768/48 = 16 out-rows (48KB)/block

// nontemporal load of a float4 (weights are streamed exactly once per call:
// rows are exclusive per (expert,part) block; keeping them out of L2/MALL
// preserves the reused t_ws/h_ws/combo lines -> r4: 121 -> 105 us).
// NOTE (r6): do NOT raise launch_bounds to (256,8) — the 64-VGPR cap serializes
// the 12 in-flight dwordx4 weight loads and costs +64%. (256,4)/44 VGPR is the
// per-wave-MLP sweet spot.
typedef float nvec4 __attribute__((ext_vector_type(4)));
__device__ __forceinline__ float4 NT4(const float4* p) {
    nvec4 v = __builtin_nontemporal_load((const nvec4*)p);
    return make_float4(v.x, v.y, v.z, v.w);
}

// ---------------- Kernel 1: fused RMSNorm + gate GEMV + top4 + softmax + packed routing ----------------
// grid = 32 blocks (one per token), 256 threads
__global__ __launch_bounds__(256) void k_prep(
    const float* __restrict__ x, const float* __restrict__ ns,
    const float* __restrict__ gw, float* __restrict__ t_ws,
    int* __restrict__ combo, float* __restrict__ out) {
    __shared__ __align__(16) float t_lds[Hdim];
    __shared__ float red_s[4];
    __shared__ __align__(16) float4 acc_s[4][32];
    __shared__ __align__(16) float gval[Edim];
    __shared__ int   sel_s[TOPK];
    __shared__ float w_s[TOPK];
    const int b    = blockIdx.x;
    const int tid  = threadIdx.x;
    const int w    = tid >> 6;
    const int lane = tid & 63;
    const float* xr = x + b * Hdim;

    // ---- RMSNorm ----
    float ss = 0.f;
    for (int i = tid; i < Hdim; i += 256) { float v = xr[i]; ss += v * v; }
#pragma unroll
    for (int off = 1; off < 64; off <<= 1) ss += __shfl_xor(ss, off, 64);
    if (lane == 0) red_s[w] = ss;
    __syncthreads();
    const float rs = rsqrtf((red_s[0] + red_s[1] + red_s[2] + red_s[3]) / (float)Hdim + 1e-5f);
    for (int i = tid; i < Hdim; i += 256) {
        float xv = xr[i];
        float tv = xv * rs * ns[i];
        t_lds[i] = tv;
        t_ws[b * Hdim + i] = tv;
        out[b * Hdim + i] = xv;          // init out = x (mlp2 atomically adds)
    }
    __syncthreads();

    // ---- gate GEMV: thread = (slice s = tid>>5 of 8, expert group g = tid&31 of 4) ----
    const int g = tid & 31;
    const int s = tid >> 5;
    const float* gwp = gw + (size_t)(s * 96) * Edim + 4 * g;
    float4 a = {0.f, 0.f, 0.f, 0.f};
#pragma unroll 8
    for (int h = 0; h < 96; ++h) {
        float tv = t_lds[s * 96 + h];
        float4 wv = *(const float4*)(gwp + (size_t)h * Edim);
        a.x += tv * wv.x; a.y += tv * wv.y;
        a.z += tv * wv.z; a.w += tv * wv.w;
    }
    a.x += __shfl_xor(a.x, 32, 64); a.y += __shfl_xor(a.y, 32, 64);
    a.z += __shfl_xor(a.z, 32, 64); a.w += __shfl_xor(a.w, 32, 64);
    if (lane < 32) acc_s[w][lane] = a;
    __syncthreads();

    if (w == 0) {
        if (lane < 32) {
            float4 s0 = acc_s[0][lane], s1 = acc_s[1][lane], s2 = acc_s[2][lane], s3 = acc_s[3][lane];
            float4 t4 = {s0.x + s1.x + s2.x + s3.x, s0.y + s1.y + s2.y + s3.y,
                         s0.z + s1.z + s2.z + s3.z, s0.w + s1.w + s2.w + s3.w};
            *(float4*)&gval[4 * lane] = t4;
        }
        // wave-0-only top-4: lane holds experts lane and lane+64
        float g0 = gval[lane], g1 = gval[lane + 64];
        bool p0 = false, p1 = false;
        float topv[TOPK]; int topi[TOPK];
#pragma unroll
        for (int k = 0; k < TOPK; ++k) {
            float c0 = p0 ? -3.0e38f : g0;
            float c1 = p1 ? -3.0e38f : g1;
            float v = fmaxf(c0, c1);
#pragma unroll
            for (int off = 1; off < 64; off <<= 1) v = fmaxf(v, __shfl_xor(v, off, 64));
            int cand = (c0 == v) ? lane : ((c1 == v) ? lane + 64 : 0x7fffffff);
#pragma unroll
            for (int off = 1; off < 64; off <<= 1) cand = min(cand, __shfl_xor(cand, off, 64));
            if (cand == lane) p0 = true;
            if (cand == lane + 64) p1 = true;
            topv[k] = v; topi[k] = cand;
        }
        if (lane == 0) {
            float m = topv[0], ex[TOPK], sum = 0.f;
#pragma unroll
            for (int k = 0; k < TOPK; ++k) { ex[k] = __expf(topv[k] - m); sum += ex[k]; }
            float inv = 1.0f / sum;
#pragma unroll
            for (int k = 0; k < TOPK; ++k) { sel_s[k] = topi[k]; w_s[k] = ex[k] * inv; }
        }
    }
    __syncthreads();
    // packed dense routing table: weight (low 2 mantissa bits cleared) | slot in low 2 bits
    if (tid < Edim) {
        int rv = 0;
#pragma unroll
        for (int k = 0; k < TOPK; ++k)
            if (sel_s[k] == tid)
                rv = (int)((__float_as_uint(w_s[k]) & ~3u) | (unsigned)k);
        combo[tid * Bdim + b] = rv;
    }
}

// ---------------- Kernel 2: mlp1 GEMV + bias + SwiGLU ----------------
__global__ __launch_bounds__(256, 4) void k_mlp1(
    const float* __restrict__ w1, const float* __restrict__ b1,
    const float* __restrict__ t_ws, const int* __restrict__ combo,
    float* __restrict__ h_ws) {
    const int e    = blockIdx.x / PARTS1;
    const int part = blockIdx.x % PARTS1;
    __shared__ float4 t_lds[CHUNK][Hdim / 4];   // 12 KiB
    __shared__ float  b1_lds[16];
    __shared__ int    pair_s[Bdim];
    __shared__ int    cnt_s;
    const int tid  = threadIdx.x;
    const int wave = tid >> 6, lane = tid & 63;

    // build token list for this expert from the packed table
    if (tid < 64) {
        int rv = (lane < Bdim) ? combo[e * Bdim + lane] : 0;
        float wv = __uint_as_float((unsigned)rv & ~3u);
        unsigned long long m = __ballot(wv > 0.f);
        if (wv > 0.f) {
            int idx = __popcll(m & ((1ull << lane) - 1ull));
            pair_s[idx] = lane * TOPK + (rv & 3);
        }
        if (lane == 0) cnt_s = (int)__popcll(m);
    }
    __syncthreads();
    const int count = cnt_s;
    if (count == 0) return;

    const int jbase = part * (Idim / PARTS1);    // 8 h-rows per block
    const float* w1e = w1 + (size_t)e * I2 * Hdim;
    if (tid < 16) b1_lds[tid] = b1[e * I2 + 2 * jbase + tid];

    for (int i0 = 0; i0 < count; i0 += CHUNK) {
        const int nt = min(CHUNK, count - i0);
        __syncthreads();   // protect LDS reuse across chunks (and order b1/pair writes)
        for (int i = 0; i < nt; ++i) {
            const float4* src = (const float4*)(t_ws + (size_t)(pair_s[i0 + i] >> 2) * Hdim);
            if (tid < Hdim / 4) t_lds[i][tid] = src[tid];
        }
        __syncthreads();
#pragma unroll
        for (int r = 0; r < 2; ++r) {
            const int j = jbase + wave * 2 + r;      // h-row in [0,768)
            const float4* rg = (const float4*)(w1e + (size_t)(2 * j) * Hdim);
            const float4* rl = (const float4*)(w1e + (size_t)(2 * j + 1) * Hdim);
            float4 g0 = NT4(rg + lane), g1 = NT4(rg + lane + 64), g2 = NT4(rg + lane + 128);
            float4 l0 = NT4(rl + lane), l1 = NT4(rl + lane + 64), l2 = NT4(rl + lane + 128);
            float ag[CHUNK], al[CHUNK];
#pragma unroll
            for (int i = 0; i < CHUNK; ++i) {
                ag[i] = 0.f; al[i] = 0.f;
                if (i < nt) {
                    float4 t0 = t_lds[i][lane], t1 = t_lds[i][lane + 64], t2 = t_lds[i][lane + 128];
                    ag[i] = g0.x*t0.x + g0.y*t0.y + g0.z*t0.z + g0.w*t0.w
                          + g1.x*t1.x + g1.y*t1.y + g1.z*t1.z + g1.w*t1.w
                          + g2.x*t2.x + g2.y*t2.y + g2.z*t2.z + g2.w*t2.w;
                    al[i] = l0.x*t0.x + l0.y*t0.y + l0.z*t0.z + l0.w*t0.w
                          + l1.x*t1.x + l1.y*t1.y + l1.z*t1.z + l1.w*t1.w
                          + l2.x*t2.x + l2.y*t2.y + l2.z*t2.z + l2.w*t2.w;
                }
            }
            const float bg = b1_lds[2 * (wave * 2 + r)];
            const float bl = b1_lds[2 * (wave * 2 + r) + 1];
#pragma unroll
            for (int i = 0; i < CHUNK; ++i) {
                if (i < nt) {
                    // parity pair-reduce: even lanes -> sum(ag), odd lanes -> sum(al)
                    const int odd = lane & 1;
                    float send = odd ? ag[i] : al[i];
                    float recv = __shfl_xor(send, 1, 64);
                    float v = (odd ? al[i] : ag[i]) + recv;
#pragma unroll
                    for (int off = 2; off < 64; off <<= 1) v += __shfl_xor(v, off, 64);
                    float vo = __shfl_xor(v, 1, 64);
                    float vg = odd ? vo : v;
                    float vl = odd ? v : vo;
                    float glu = fminf(vg + bg, 7.0f);
                    float lin = fminf(fmaxf(vl + bl, -7.0f), 7.0f);
                    float og = glu / (1.0f + __expf(-1.702f * glu));
                    if (lane == 0)
                        h_ws[(size_t)pair_s[i0 + i] * Idim + j] = og * (lin + 1.0f);
                }
            }
        }
    }
}

// ---------------- Kernel 3: mlp2 GEMV + bias, weighted atomic accumulate into out ----------------
__global__ __launch_bounds__(256, 4) void k_mlp2(
    const float* __restrict__ w2, const float* __restrict__ b2,
    const float* __restrict__ h_ws, const int* __restrict__ combo,
    float* __restrict__ out) {
    const int e    = blockIdx.x / PARTS2;
    const int part = blockIdx.x % PARTS2;
    __shared__ float4 h_lds[CHUNK][Idim / 4];   // 12 KiB
    __shared__ float  b2_lds[16];
    __shared__ int    pair_s[Bdim];
    __shared__ float  wt_s[Bdim];
    __shared__ int    cnt_s;
    const int tid  = threadIdx.x;
    const int wave = tid >> 6, lane = tid & 63;

    if (tid < 64) {
        int rv = (lane < Bdim) ? combo[e * Bdim + lane] : 0;
        float wv = __uint_as_float((unsigned)rv & ~3u);
        unsigned long long m = __ballot(wv > 0.f);
        if (wv > 0.f) {
            int idx = __popcll(m & ((1ull << lane) - 1ull));
            pair_s[idx] = lane * TOPK + (rv & 3);
            wt_s[idx]   = wv;
        }
        if (lane == 0) cnt_s = (int)__popcll(m);
    }
    __syncthreads();
    const int count = cnt_s;
    if (count == 0) return;

    const int cbase = part * (Hdim / PARTS2);    // 16 out-rows per block
    const float* w2e = w2 + (size_t)e * Hdim * Idim;
    if (tid < 16) b2_lds[tid] = b2[e * Hdim + cbase + tid];

    for (int i0 = 0; i0 < count; i0 += CHUNK) {
        const int nt = min(CHUNK, count - i0);
        __syncthreads();
        for (int i = 0; i < nt; ++i) {
            const float4* src = (const float4*)(h_ws + (size_t)pair_s[i0 + i] * Idim);
            if (tid < Idim / 4) h_lds[i][tid] = src[tid];
        }
        __syncthreads();
#pragma unroll
        for (int rp = 0; rp < 2; ++rp) {            // row pairs
            const int c0 = cbase + wave * 4 + 2 * rp;
            const float4* r0 = (const float4*)(w2e + (size_t)c0 * Idim);
            const float4* r1 = (const float4*)(w2e + (size_t)(c0 + 1) * Idim);
            float4 a0 = NT4(r0 + lane), a1 = NT4(r0 + lane + 64), a2 = NT4(r0 + lane + 128);
            float4 d0 = NT4(r1 + lane), d1 = NT4(r1 + lane + 64), d2 = NT4(r1 + lane + 128);
            float ao0[CHUNK], ao1[CHUNK];
#pragma unroll
            for (int i = 0; i < CHUNK; ++i) {
                ao0[i] = 0.f; ao1[i] = 0.f;
                if (i < nt) {
                    float4 h0 = h_lds[i][lane], h1 = h_lds[i][lane + 64], h2 = h_lds[i][lane + 128];
                    ao0[i] = a0.x*h0.x + a0.y*h0.y + a0.z*h0.z + a0.w*h0.w
                           + a1.x*h1.x + a1.y*h1.y + a1.z*h1.z + a1.w*h1.w
                           + a2.x*h2.x + a2.y*h2.y + a2.z*h2.z + a2.w*h2.w;
                    ao1[i] = d0.x*h0.x + d0.y*h0.y + d0.z*h0.z + d0.w*h0.w
                           + d1.x*h1.x + d1.y*h1.y + d1.z*h1.z + d1.w*h1.w
                           + d2.x*h2.x + d2.y*h2.y + d2.z*h2.z + d2.w*h2.w;
                }
            }
#pragma unroll
            for (int i = 0; i < CHUNK; ++i) {
                if (i < nt) {
                    // parity pair-reduce: even lanes -> sum(ao0), odd -> sum(ao1)
                    const int odd = lane & 1;
                    float send = odd ? ao0[i] : ao1[i];
                    float recv = __shfl_xor(send, 1, 64);
                    float v = (odd ? ao1[i] : ao0[i]) + recv;
#pragma unroll
                    for (int off = 2; off < 64; off <<= 1) v += __shfl_xor(v, off, 64);
                    const int c = c0 + odd;
                    if (lane < 2)
                        atomicAdd(&out[(size_t)(pair_s[i0 + i] >> 2) * Hdim + c],
                                  (v + b2_lds[c - cbase]) * wt_s[i0 + i]);
                }
            }
        }
    }
}

extern "C" void kernel_launch(void* const* d_in, const int* in_sizes, int n_in,
                              void* d_out, int out_size, void* d_ws, size_t ws_size,
                              hipStream_t stream) {
    const float* x  = (const float*)d_in[0];
    const float* ns = (const float*)d_in[1];
    const float* gw = (const float*)d_in[2];
    const float* w1 = (const float*)d_in[3];
    const float* b1 = (const float*)d_in[4];
    const float* w2 = (const float*)d_in[5];
    const float* b2 = (const float*)d_in[6];
    float* out = (float*)d_out;
    float* ws  = (float*)d_ws;

    // workspace layout (float offsets)
    float* t_ws  = ws;                     // 32*768  = 24576
    int*   combo = (int*)(ws + 24576);     // 128*32  = 4096 (packed weight|slot)
    float* h_ws  = ws + 28672;             // 128*768 = 98304
    // total: 126976 floats = 507,904 bytes

    k_prep<<<Bdim, 256, 0, stream>>>(x, ns, gw, t_ws, combo, out);
    k_mlp1<<<Edim * PARTS1, 256, 0, stream>>>(w1, b1, t_ws, combo, h_ws);
    k_mlp2<<<Edim * PARTS2, 256, 0, stream>>>(w2, b2, h_ws, combo, out);
}